// Round 3
// baseline (2039.760 us; speedup 1.0000x reference)
//
#include <hip/hip_runtime.h>
#include <hip/hip_bf16.h>
#include <stdint.h>

// StackedContextViT forward, MI355X gfx950. ALL inputs/outputs are FLOAT32.
// Internal: bf16 storage + bf16 MFMA, f32 accumulate, f32 epilogue math.
// B=4 N=1024 PD=768 D=768 H=12 HD=64 L=6 F=3072 V=1024 G=32
// ws base (known safe, 15.73MB): [0]mode | X bf16[4096,768] | WA | WB
// ws extra (if >=25.2MB): QK[4096,1536] | VT[48*64,1024] | O[4096,768]  (attn)
//                         H[4096,3072]                                  (ffn, aliased)
// d_out (16.79MB) is scratch until the head GEMM writes f32 logits.
//
// R3: (a) 6-stage LDS pipeline (48KB), steady-state vmcnt(8) = 4 tiles in
//     flight -> exposed per-iter latency ~ lat/4 (R2 was depth-3, slack 1,
//     iter ~1100cy). Branchless steady loop + cold drain.
//     (b) bank-conflict fix: row stride is 64B = 16 banks (alias period 2
//     rows), so the K-slot XOR must be ((row>>1)&3), not (row&3). R2's
//     wrong XOR measured 4-way (4.7M conflict-cycles); this is 2-way=free.

#define BM 64
#define BN 64
#define BK 32

using u16 = unsigned short;
typedef __attribute__((ext_vector_type(8))) short short8;
typedef __attribute__((ext_vector_type(4))) float f32x4;
typedef __attribute__((ext_vector_type(4))) u16 u16x4;

#define GPTR(p) ((const __attribute__((address_space(1))) void*)(p))
#define LPTR(p) ((__attribute__((address_space(3))) void*)(p))

__device__ __forceinline__ float b2f(u16 u){
  union { unsigned int i; float f; } x; x.i = ((unsigned int)u) << 16; return x.f;
}
__device__ __forceinline__ u16 f2b(float f){
  f = fminf(fmaxf(f, -448.0f), 448.0f);
  union { float f; unsigned int i; } x; x.f = f;
  unsigned int r = x.i + 0x7FFFu + ((x.i >> 16) & 1u);
  return (u16)(r >> 16);
}

// ---- mask dtype detection: 0=u8 bool, 1=bf16, 2=f32, 3=i32 ----
__global__ __launch_bounds__(256) void detect_k(const u16* __restrict__ mk, int* __restrict__ mode){
  __shared__ int f[3];
  int tid = threadIdx.x;
  if (tid < 3) f[tid] = 0;
  __syncthreads();
  for (int i = tid; i < 2048; i += 256){
    u16 u = mk[i];
    if (u == 256 || u == 257) atomicOr(&f[0], 1);
    if (u == 0x3F80){ if ((i & 1) == 0) atomicOr(&f[1], 1); else atomicOr(&f[2], 1); }
  }
  __syncthreads();
  if (tid == 0){
    int m;
    if (f[0]) m = 0;
    else if (f[1]) m = 1;
    else if (f[2]) m = 2;
    else m = 3;
    *mode = m;
  }
}

__device__ __forceinline__ bool mask_at(const void* mk, int mode, int i){
  if (mode == 0) return ((const unsigned char*)mk)[i] != 0;
  if (mode == 1) return ((const u16*)mk)[i] != 0;
  if (mode == 2) return ((const float*)mk)[i] != 0.0f;
  return ((const int*)mk)[i] != 0;
}

// ---- f32 weight -> bf16 staging ----
__global__ __launch_bounds__(256) void wconv_k(const float* __restrict__ src, u16* __restrict__ dst){
  long i = ((long)blockIdx.x * 256 + threadIdx.x) * 4;
  float4 v = *(const float4*)(src + i);
  u16x4 o; o.x = f2b(v.x); o.y = f2b(v.y); o.z = f2b(v.z); o.w = f2b(v.w);
  *(u16x4*)(dst + i) = o;
}

// ---- masked-patch select + f32->bf16 (full 4096 rows) ----
__global__ __launch_bounds__(256) void embed_k(const float* __restrict__ patches, const void* __restrict__ mask,
                                               const int* __restrict__ mode, const float* __restrict__ mtok,
                                               u16* __restrict__ MP){
  int row = blockIdx.x;
  bool m = mask_at(mask, *mode, row);
  int tid = threadIdx.x;
  long base = (long)row * 768;
  #pragma unroll
  for (int i = 0; i < 3; i++){
    int p = tid + i * 256;
    MP[base + p] = f2b(m ? mtok[p] : patches[base + p]);
  }
}

// ---- mask echo (output #2, f32 0/1) ----
__global__ __launch_bounds__(256) void maskout_k(const void* __restrict__ mask, const int* __restrict__ mode,
                                                 float* __restrict__ out){
  int i = blockIdx.x * 256 + threadIdx.x;
  out[i] = mask_at(mask, *mode, i) ? 1.0f : 0.0f;
}

// ---- layernorm over D=768 (bf16 in/out, f32 params+math) ----
__global__ __launch_bounds__(256) void ln_k(const u16* __restrict__ XR, u16* __restrict__ X,
                                            const float* __restrict__ s, const float* __restrict__ b){
  int row = blockIdx.x;
  int tid = threadIdx.x;
  const u16* xr = XR + (long)row * 768;
  float v0 = b2f(xr[tid]), v1 = b2f(xr[tid + 256]), v2 = b2f(xr[tid + 512]);
  float sum = v0 + v1 + v2, sq = v0 * v0 + v1 * v1 + v2 * v2;
  #pragma unroll
  for (int off = 32; off; off >>= 1){ sum += __shfl_xor(sum, off); sq += __shfl_xor(sq, off); }
  __shared__ float ls[4], lq[4];
  int wave = tid >> 6, lane = tid & 63;
  if (lane == 0){ ls[wave] = sum; lq[wave] = sq; }
  __syncthreads();
  sum = ls[0] + ls[1] + ls[2] + ls[3];
  sq  = lq[0] + lq[1] + lq[2] + lq[3];
  float mu = sum * (1.0f / 768.0f);
  float var = fmaxf(sq * (1.0f / 768.0f) - mu * mu, 0.0f);
  float rs = rsqrtf(var + 1e-5f);
  u16* xo = X + (long)row * 768;
  xo[tid]       = f2b((v0 - mu) * rs * s[tid]       + b[tid]);
  xo[tid + 256] = f2b((v1 - mu) * rs * s[tid + 256] + b[tid + 256]);
  xo[tid + 512] = f2b((v2 - mu) * rs * s[tid + 512] + b[tid + 512]);
}

// ---- softmax over rows of 1024 (in place, bf16), one wave per row ----
// vectorized: each lane owns 16 contiguous elems (2x short8)
__global__ __launch_bounds__(256) void softmax_k(u16* __restrict__ S){
  long row = (long)blockIdx.x * 4 + (threadIdx.x >> 6);
  u16* p = S + row * 1024;
  int lane = threadIdx.x & 63;
  short8 a = *(const short8*)&p[lane * 16];
  short8 b = *(const short8*)&p[lane * 16 + 8];
  float v[16]; float mx = -1e30f;
  #pragma unroll
  for (int i = 0; i < 8; i++){ v[i] = b2f((u16)a[i]); v[i + 8] = b2f((u16)b[i]); }
  #pragma unroll
  for (int i = 0; i < 16; i++) mx = fmaxf(mx, v[i]);
  #pragma unroll
  for (int off = 32; off; off >>= 1) mx = fmaxf(mx, __shfl_xor(mx, off));
  float sum = 0.0f;
  #pragma unroll
  for (int i = 0; i < 16; i++){ v[i] = __expf(v[i] - mx); sum += v[i]; }
  #pragma unroll
  for (int off = 32; off; off >>= 1) sum += __shfl_xor(sum, off);
  float inv = 1.0f / sum;
  #pragma unroll
  for (int i = 0; i < 8; i++){ a[i] = (short)f2b(v[i] * inv); b[i] = (short)f2b(v[i + 8] * inv); }
  *(short8*)&p[lane * 16] = a;
  *(short8*)&p[lane * 16 + 8] = b;
}

// ---- generic bf16 MFMA GEMM: C = A[.,K] * W[N,K]^T (+ epilogue) ----
// 64x64 tile, 4 waves each 32x32, 6-stage pipelined K-loop. EPI as before.
struct GP {
  const u16* A; const u16* W; u16* C; float* Cf;
  const float* bias; const float* relb; const float* pose;
  const u16* resid;
  u16* Cv;
  long sAz, sWz, sCz;
  int lda, ldw, ldc;
  int N, K;
  int wclamp, zBase;
  float scale;
};

template<int EPI>
__global__ __launch_bounds__(256)
void gemm_k(GP g){
  __shared__ __align__(16) u16 As[6][BM * BK];
  __shared__ __align__(16) u16 Bs[6][BN * BK];
  const int tid  = threadIdx.x;
  const int wave = tid >> 6, lane = tid & 63;
  const int quad = lane >> 4, l16 = lane & 15;
  const int wm = wave >> 1, wn = wave & 1;

  // bijective XCD-aware swizzle over the 2D (x,y) plane (m204)
  const int gx = gridDim.x;
  const int nwg = gx * gridDim.y;
  int bid = blockIdx.y * gx + blockIdx.x;
  {
    const int q = nwg >> 3, r = nwg & 7;
    const int xcd = bid & 7, loc = bid >> 3;
    bid = (xcd < r ? xcd * (q + 1) : r * (q + 1) + (xcd - r) * q) + loc;
  }
  const int m0 = (bid / gx) * BM;
  const int n0 = (bid % gx) * BN;
  const int z = blockIdx.z;

  const u16* Ab;
  const u16* Wb;
  if constexpr (EPI == 1){
    // per-head Q/K bases inside QK[rows,1536]: Q cols h*64, K cols 768+h*64
    int hh = g.zBase + z;
    int b = hh / 12, h = hh - b * 12;
    Ab = g.A + (long)b * 1572864 + h * 64;
    Wb = Ab + 768;
  } else {
    Ab = g.A + (long)z * g.sAz;
    Wb = g.W + (long)z * g.sWz;
  }

  f32x4 acc[2][2];
  #pragma unroll
  for (int i = 0; i < 2; i++)
    #pragma unroll
    for (int j = 0; j < 2; j++) acc[i][j] = (f32x4){0.f, 0.f, 0.f, 0.f};

  // staging: c0 = wave*64+lane in [0,256); row = c0>>2, 16B-slot = c0&3.
  // K-slot XOR swizzle (both sides, rule #21): row stride 64B = 16 banks
  // aliases with period 2 rows, so XOR with ((row>>1)&3). LDS dest linear;
  // reads un-XOR with (quad ^ ((l16>>1)&3)).
  const int c0 = wave * 64 + lane;
  const int arow = c0 >> 2, aslot = (c0 & 3) ^ ((arow >> 1) & 3);
  const u16* a0 = Ab + (long)(m0 + arow) * g.lda + aslot * 8;
  const u16* w0 = Wb + (long)min(n0 + arow, g.wclamp) * g.ldw + aslot * 8;
  const int o0 = wave * 512;  // u16 elems into stage (wave*1024 bytes)

  const int nt = g.K / BK;
  const int rs = (quad ^ ((l16 >> 1) & 3)) * 8;  // read slot (elems)

  // stage tile kt into LDS buffer sb (2 global_load_lds = 2 vmcnt events/wave)
  #define STAGE(sb, kt) do { \
    __builtin_amdgcn_global_load_lds(GPTR(a0 + (kt)), LPTR(&As[(sb)][o0]), 16, 0, 0); \
    __builtin_amdgcn_global_load_lds(GPTR(w0 + (kt)), LPTR(&Bs[(sb)][o0]), 16, 0, 0); \
  } while (0)

  #define COMPUTE(sb) do { \
    short8 af[2], bf[2]; \
    af[0] = *(const short8*)&As[(sb)][(wm * 32 + l16) * BK + rs]; \
    af[1] = *(const short8*)&As[(sb)][(wm * 32 + 16 + l16) * BK + rs]; \
    bf[0] = *(const short8*)&Bs[(sb)][(wn * 32 + l16) * BK + rs]; \
    bf[1] = *(const short8*)&Bs[(sb)][(wn * 32 + 16 + l16) * BK + rs]; \
    acc[0][0] = __builtin_amdgcn_mfma_f32_16x16x32_bf16(af[0], bf[0], acc[0][0], 0, 0, 0); \
    acc[0][1] = __builtin_amdgcn_mfma_f32_16x16x32_bf16(af[0], bf[1], acc[0][1], 0, 0, 0); \
    acc[1][0] = __builtin_amdgcn_mfma_f32_16x16x32_bf16(af[1], bf[0], acc[1][0], 0, 0, 0); \
    acc[1][1] = __builtin_amdgcn_mfma_f32_16x16x32_bf16(af[1], bf[1], acc[1][1], 0, 0, 0); \
  } while (0)

  // prologue: stage up to 5 tiles; wait for tile 0 only (rest in flight)
  const int pre = nt < 5 ? nt : 5;
  for (int i = 0; i < pre; ++i) STAGE(i, i * BK);
  switch (pre){
    case 5:  asm volatile("s_waitcnt vmcnt(8)\n\ts_barrier" ::: "memory"); break;
    case 4:  asm volatile("s_waitcnt vmcnt(6)\n\ts_barrier" ::: "memory"); break;
    case 3:  asm volatile("s_waitcnt vmcnt(4)\n\ts_barrier" ::: "memory"); break;
    case 2:  asm volatile("s_waitcnt vmcnt(2)\n\ts_barrier" ::: "memory"); break;
    default: asm volatile("s_waitcnt vmcnt(0)\n\ts_barrier" ::: "memory"); break;
  }

  // steady state: stage tile t+5, compute tile t, wait with 4 tiles in flight
  int t = 0, sC = 0, sP = 5;
  for (; t + 5 < nt; ++t){
    STAGE(sP, (t + 5) * BK);
    COMPUTE(sC);
    asm volatile("s_waitcnt vmcnt(8) lgkmcnt(0)\n\ts_barrier" ::: "memory");
    sC = sC == 5 ? 0 : sC + 1;
    sP = sP == 5 ? 0 : sP + 1;
  }
  // drain: no more staging; vmcnt tracks remaining in-flight tiles
  for (; t < nt; ++t){
    COMPUTE(sC);
    if (t + 1 < nt){
      const int c = nt - 2 - t;  // tiles t+2..nt-1 still in flight (<=3 here)
      if      (c >= 3) asm volatile("s_waitcnt vmcnt(6) lgkmcnt(0)\n\ts_barrier" ::: "memory");
      else if (c == 2) asm volatile("s_waitcnt vmcnt(4) lgkmcnt(0)\n\ts_barrier" ::: "memory");
      else if (c == 1) asm volatile("s_waitcnt vmcnt(2) lgkmcnt(0)\n\ts_barrier" ::: "memory");
      else             asm volatile("s_waitcnt vmcnt(0) lgkmcnt(0)\n\ts_barrier" ::: "memory");
    }
    sC = sC == 5 ? 0 : sC + 1;
  }
  #undef STAGE
  #undef COMPUTE

  // epilogue: C/D layout col=lane&15, row=quad*4+reg
  #pragma unroll
  for (int i = 0; i < 2; i++){
    #pragma unroll
    for (int j = 0; j < 2; j++){
      #pragma unroll
      for (int rr = 0; rr < 4; rr++){
        const long r = (long)m0 + wm * 32 + i * 16 + quad * 4 + rr;
        const int  c = n0 + wn * 32 + j * 16 + l16;
        if (c >= g.N) continue;
        float v = acc[i][j][rr];
        if constexpr (EPI == 0){            // qkv: QK natural, V transposed per head
          u16 o = f2b(v + g.bias[c]);
          if (c < 1536) g.C[r * 1536 + c] = o;
          else {
            int c2 = c - 1536;
            int hh = ((int)(r >> 10)) * 12 + (c2 >> 6);
            g.Cv[((long)hh * 64 + (c2 & 63)) * 1024 + (r & 1023)] = o;
          }
        } else if constexpr (EPI == 1){     // scores: *scale + f32 Swin rel-bias
          const int rq = (int)r;
          const int ir = (rq >> 5) - (c >> 5) + 31;
          const int ic = (rq & 31) - (c & 31) + 31;
          float val = v * g.scale + g.relb[ir * 63 + ic];
          (g.C + (long)z * g.sCz)[(long)rq * 1024 + c] = f2b(val);
        } else if constexpr (EPI == 2){     // pv -> O[bg*1024+r][h*64+c]
          int hh = g.zBase + z;
          int bg = hh / 12, h = hh - bg * 12;
          g.C[((long)bg * 1024 + r) * 768 + h * 64 + c] = f2b(v);
        } else if constexpr (EPI == 3){     // bias + residual
          long o = r * (long)g.ldc + c;
          g.C[o] = f2b(v + g.bias[c] + b2f(g.resid[o]));
        } else if constexpr (EPI == 4){     // bias + exact gelu
          float t2 = v + g.bias[c];
          g.C[r * (long)g.ldc + c] = f2b(0.5f * t2 * (1.0f + erff(t2 * 0.70710678118654752f)));
        } else if constexpr (EPI == 5){     // bias -> f32 output (head)
          float t2 = v + g.bias[c];
          t2 = fminf(fmaxf(t2, -1.0e4f), 1.0e4f);
          g.Cf[r * (long)g.ldc + c] = t2;
        } else {                            // bias + pos_emb
          float val = v + g.bias[c] + g.pose[(long)(r & 1023) * 768 + c];
          g.C[r * (long)g.ldc + c] = f2b(val);
        }
      }
    }
  }
}

static inline void glaunch(int epi, dim3 grid, const GP& g, hipStream_t stream){
  switch (epi){
    case 0: gemm_k<0><<<grid, dim3(256), 0, stream>>>(g); break;
    case 1: gemm_k<1><<<grid, dim3(256), 0, stream>>>(g); break;
    case 2: gemm_k<2><<<grid, dim3(256), 0, stream>>>(g); break;
    case 3: gemm_k<3><<<grid, dim3(256), 0, stream>>>(g); break;
    case 4: gemm_k<4><<<grid, dim3(256), 0, stream>>>(g); break;
    case 5: gemm_k<5><<<grid, dim3(256), 0, stream>>>(g); break;
    default: gemm_k<6><<<grid, dim3(256), 0, stream>>>(g); break;
  }
}

extern "C" void kernel_launch(void* const* d_in, const int* in_sizes, int n_in,
                              void* d_out, int out_size, void* d_ws, size_t ws_size,
                              hipStream_t stream){
  (void)in_sizes; (void)n_in; (void)out_size;
  const float* patches = (const float*)d_in[0];
  const void*  mask    = d_in[1];
  const float* mtok    = (const float*)d_in[2];
  const float* patch_w = (const float*)d_in[3];
  const float* patch_b = (const float*)d_in[4];
  const float* pos_emb = (const float*)d_in[5];
  const float* rel_b   = (const float*)d_in[6];
  const float* in_w    = (const float*)d_in[7];
  const float* in_b    = (const float*)d_in[8];
  const float* attn_ow = (const float*)d_in[9];
  const float* attn_ob = (const float*)d_in[10];
  const float* ln1_s   = (const float*)d_in[11];
  const float* ln1_b   = (const float*)d_in[12];
  const float* ffn_w1  = (const float*)d_in[13];
  const float* ffn_b1  = (const float*)d_in[14];
  const float* ffn_w2  = (const float*)d_in[15];
  const float* ffn_b2  = (const float*)d_in[16];
  const float* ln2_s   = (const float*)d_in[17];
  const float* ln2_b   = (const float*)d_in[18];
  const float* head_w  = (const float*)d_in[19];
  const float* head_b  = (const float*)d_in[20];

  // ws base layout (known safe)
  char* ws = (char*)d_ws;
  int* mode = (int*)ws;
  u16* X  = (u16*)(ws + 256);            // [4096,768]
  u16* WA = X + 3145728;                 // up to [3072,768]
  u16* WB = WA + 2359296;                // up to [3072,768]
  char* EX = (char*)(WB + 2359296);      // extra region
  long extra = (long)ws_size - 15728896L;
  const bool bigWs = extra >= 25165824L; // QK+VT+O (= H) fits in ws extra

  u16*   dout16 = (u16*)d_out;
  float* doutf  = (float*)d_out;

  // big-ws pointers (attention phase)
  u16* QKp = (u16*)EX;                   // [4096,1536]
  u16* VTp = QKp + 6291456;              // [48*64,1024]
  u16* Op  = VTp + 3145728;              // [4096,768]
  u16* Hp  = (u16*)EX;                   // [4096,3072] (ffn phase, aliased)
  // big-ws S placement: prefer leftover ws-extra, else d_out (8 slabs)
  long extra2 = extra - 25165824L;
  u16* Sp_big; int SCH_big;
  if (extra2 >= 4194304L){
    Sp_big = Op + 3145728;
    SCH_big = (int)(extra2 / 2097152L); if (SCH_big > 48) SCH_big = 48;
  } else {
    Sp_big = dout16; SCH_big = 8;
  }
  // small-ws pointers: S in ws extra, attention staged in d_out halves
  u16* Sp_small = (u16*)EX;
  int SCH_small = (int)(extra / 2097152L);
  if (SCH_small < 1) SCH_small = 1;
  if (SCH_small > 24) SCH_small = 24;
  u16* O16  = dout16;                    // [4096,768]
  u16* QKh  = dout16 + 3145728;          // [2048,1536]
  u16* VTh  = dout16 + 6291456;          // [24*64,1024]
  u16* XRb  = dout16 + 3145728;          // [4096,768] (after QKh/VTh dead)
  u16* Hc   = dout16;                    // [2048,3072]
  u16* XRc  = dout16 + 6291456;          // [2048,768]

  detect_k<<<dim3(1), dim3(256), 0, stream>>>((const u16*)mask, mode);

  GP g;
  // embed (MP in d_out) + patch projection -> X
  wconv_k<<<dim3(576), dim3(256), 0, stream>>>(patch_w, WA);
  embed_k<<<dim3(4096), dim3(256), 0, stream>>>(patches, mask, mode, mtok, dout16);
  g = {};
  g.A = dout16; g.lda = 768; g.W = WA; g.ldw = 768; g.wclamp = 767;
  g.C = X; g.ldc = 768; g.N = 768; g.K = 768;
  g.bias = patch_b; g.pose = pos_emb;
  glaunch(6, dim3(12, 64, 1), g, stream);

  for (int l = 0; l < 6; l++){
    wconv_k<<<dim3(1728), dim3(256), 0, stream>>>(in_w + (long)l * 1769472, WA);
    wconv_k<<<dim3(576),  dim3(256), 0, stream>>>(attn_ow + (long)l * 589824, WB);

    if (bigWs){
      // qkv full-M
      g = {};
      g.A = X; g.lda = 768; g.W = WA; g.ldw = 768; g.wclamp = 2303;
      g.bias = in_b + (long)l * 2304;
      g.C = QKp; g.Cv = VTp; g.N = 2304; g.K = 768;
      glaunch(0, dim3(36, 64, 1), g, stream);

      for (int ch0 = 0; ch0 < 48; ch0 += SCH_big){
        int zc = (48 - ch0 < SCH_big) ? (48 - ch0) : SCH_big;
        g = {};
        g.A = QKp; g.lda = 1536; g.zBase = ch0;
        g.C = Sp_big; g.sCz = 1048576; g.N = 1024; g.K = 64;
        g.relb = rel_b; g.scale = 0.125f; g.wclamp = 1023;
        glaunch(1, dim3(16, 16, zc), g, stream);
        softmax_k<<<dim3(zc * 256), dim3(256), 0, stream>>>(Sp_big);
        g = {};
        g.A = Sp_big; g.lda = 1024; g.sAz = 1048576;
        g.W = VTp + (long)ch0 * 65536; g.ldw = 1024; g.sWz = 65536; g.wclamp = 63;
        g.C = Op; g.zBase = ch0; g.N = 64; g.K = 1024;
        glaunch(2, dim3(1, 16, zc), g, stream);
      }

      // o-proj + residual -> XR(d_out), LN1 -> X
      g = {};
      g.A = Op; g.lda = 768; g.W = WB; g.ldw = 768; g.wclamp = 767;
      g.bias = attn_ob + (long)l * 768; g.resid = X;
      g.C = dout16; g.ldc = 768; g.N = 768; g.K = 768;
      glaunch(3, dim3(12, 64, 1), g, stream);
      ln_k<<<dim3(4096), dim3(256), 0, stream>>>(dout16, X, ln1_s + l * 768, ln1_b + l * 768);
    } else {
      for (int hb = 0; hb < 2; hb++){
        g = {};
        g.A = X + (long)hb * 1572864; g.lda = 768;
        g.W = WA; g.ldw = 768; g.wclamp = 2303;
        g.bias = in_b + (long)l * 2304;
        g.C = QKh; g.Cv = VTh; g.N = 2304; g.K = 768;
        glaunch(0, dim3(36, 32, 1), g, stream);

        for (int ch0 = 0; ch0 < 24; ch0 += SCH_small){
          int zc = (24 - ch0 < SCH_small) ? (24 - ch0) : SCH_small;
          g = {};
          g.A = QKh; g.lda = 1536; g.zBase = ch0;          // b local in {0,1}
          g.C = Sp_small; g.sCz = 1048576; g.N = 1024; g.K = 64;
          g.relb = rel_b; g.scale = 0.125f; g.wclamp = 1023;
          glaunch(1, dim3(16, 16, zc), g, stream);
          softmax_k<<<dim3(zc * 256), dim3(256), 0, stream>>>(Sp_small);
          g = {};
          g.A = Sp_small; g.lda = 1024; g.sAz = 1048576;
          g.W = VTh + (long)ch0 * 65536; g.ldw = 1024; g.sWz = 65536; g.wclamp = 63;
          g.C = O16; g.zBase = hb * 24 + ch0; g.N = 64; g.K = 1024;
          glaunch(2, dim3(1, 16, zc), g, stream);
        }
      }
      g = {};
      g.A = O16; g.lda = 768; g.W = WB; g.ldw = 768; g.wclamp = 767;
      g.bias = attn_ob + (long)l * 768; g.resid = X;
      g.C = XRb; g.ldc = 768; g.N = 768; g.K = 768;
      glaunch(3, dim3(12, 64, 1), g, stream);
      ln_k<<<dim3(4096), dim3(256), 0, stream>>>(XRb, X, ln1_s + l * 768, ln1_b + l * 768);
    }

    wconv_k<<<dim3(2304), dim3(256), 0, stream>>>(ffn_w1 + (long)l * 2359296, WA);
    wconv_k<<<dim3(2304), dim3(256), 0, stream>>>(ffn_w2 + (long)l * 2359296, WB);

    if (bigWs){
      g = {};
      g.A = X; g.lda = 768; g.W = WA; g.ldw = 768; g.wclamp = 3071;
      g.bias = ffn_b1 + (long)l * 3072;
      g.C = Hp; g.ldc = 3072; g.N = 3072; g.K = 768;
      glaunch(4, dim3(48, 64, 1), g, stream);
      g = {};
      g.A = Hp; g.lda = 3072; g.W = WB; g.ldw = 3072; g.wclamp = 767;
      g.bias = ffn_b2 + (long)l * 768; g.resid = X;
      g.C = dout16; g.ldc = 768; g.N = 768; g.K = 3072;
      glaunch(3, dim3(12, 64, 1), g, stream);
      ln_k<<<dim3(4096), dim3(256), 0, stream>>>(dout16, X, ln2_s + l * 768, ln2_b + l * 768);
    } else {
      for (int cc = 0; cc < 2; cc++){
        u16* Xc = X + (long)cc * 1572864;
        g = {};
        g.A = Xc; g.lda = 768; g.W = WA; g.ldw = 768; g.wclamp = 3071;
        g.bias = ffn_b1 + (long)l * 3072;
        g.C = Hc; g.ldc = 3072; g.N = 3072; g.K = 768;
        glaunch(4, dim3(48, 32, 1), g, stream);
        g = {};
        g.A = Hc; g.lda = 3072; g.W = WB; g.ldw = 3072; g.wclamp = 767;
        g.bias = ffn_b2 + (long)l * 768; g.resid = Xc;
        g.C = XRc; g.ldc = 768; g.N = 768; g.K = 3072;
        glaunch(3, dim3(12, 32, 1), g, stream);
        ln_k<<<dim3(2048), dim3(256), 0, stream>>>(XRc, Xc, ln2_s + l * 768, ln2_b + l * 768);
      }
    }
  }

  // head: logits (f32) -> d_out
  wconv_k<<<dim3(768), dim3(256), 0, stream>>>(head_w, WA);
  g = {};
  g.A = X; g.lda = 768; g.W = WA; g.ldw = 768; g.wclamp = 1023;
  g.bias = head_b;
  g.Cf = doutf; g.ldc = 1024; g.N = 1024; g.K = 768;
  glaunch(5, dim3(16, 64, 1), g, stream);
  maskout_k<<<dim3(16), dim3(256), 0, stream>>>(mask, mode, doutf + 4194304);
}

// Round 4
// 1855.430 us; speedup vs baseline: 1.0993x; 1.0993x over previous
//
#include <hip/hip_runtime.h>
#include <hip/hip_bf16.h>
#include <stdint.h>

// StackedContextViT forward, MI355X gfx950. ALL inputs/outputs are FLOAT32.
// Internal: bf16 storage + bf16 MFMA, f32 accumulate, f32 epilogue math.
// B=4 N=1024 PD=768 D=768 H=12 HD=64 L=6 F=3072 V=1024 G=32
// ws base (known safe, 15.73MB): [0]mode | X bf16[4096,768] | WA | WB
// ws extra (if >=25.2MB): QK[4096,1536] | VT[48*64,1024] | O[4096,768]  (attn)
//                         H[4096,3072]                                  (ffn, aliased)
// d_out (16.79MB) is scratch until the head GEMM writes f32 logits.
//
// R4: (a) revert GEMM K-loop to 3-stage/24KB (R2 structure; R3's 6-stage
//     traded occupancy for useless latency slack - staging-pipe bound, not
//     latency bound). Keep R3's verified conflict-free XOR ((row>>1)&3).
//     (b) flash-attention kernel replaces scores+softmax+pv: S (96MB/layer,
//     touched 4x) never materialized. Online softmax in f32, P relayed via
//     LDS using the same verified swizzle layout as the GEMM staging.

#define BM 64
#define BN 64
#define BK 32

using u16 = unsigned short;
typedef __attribute__((ext_vector_type(8))) short short8;
typedef __attribute__((ext_vector_type(4))) float f32x4;
typedef __attribute__((ext_vector_type(4))) u16 u16x4;

#define GPTR(p) ((const __attribute__((address_space(1))) void*)(p))
#define LPTR(p) ((__attribute__((address_space(3))) void*)(p))

__device__ __forceinline__ float b2f(u16 u){
  union { unsigned int i; float f; } x; x.i = ((unsigned int)u) << 16; return x.f;
}
__device__ __forceinline__ u16 f2b(float f){
  f = fminf(fmaxf(f, -448.0f), 448.0f);
  union { float f; unsigned int i; } x; x.f = f;
  unsigned int r = x.i + 0x7FFFu + ((x.i >> 16) & 1u);
  return (u16)(r >> 16);
}

// ---- mask dtype detection: 0=u8 bool, 1=bf16, 2=f32, 3=i32 ----
__global__ __launch_bounds__(256) void detect_k(const u16* __restrict__ mk, int* __restrict__ mode){
  __shared__ int f[3];
  int tid = threadIdx.x;
  if (tid < 3) f[tid] = 0;
  __syncthreads();
  for (int i = tid; i < 2048; i += 256){
    u16 u = mk[i];
    if (u == 256 || u == 257) atomicOr(&f[0], 1);
    if (u == 0x3F80){ if ((i & 1) == 0) atomicOr(&f[1], 1); else atomicOr(&f[2], 1); }
  }
  __syncthreads();
  if (tid == 0){
    int m;
    if (f[0]) m = 0;
    else if (f[1]) m = 1;
    else if (f[2]) m = 2;
    else m = 3;
    *mode = m;
  }
}

__device__ __forceinline__ bool mask_at(const void* mk, int mode, int i){
  if (mode == 0) return ((const unsigned char*)mk)[i] != 0;
  if (mode == 1) return ((const u16*)mk)[i] != 0;
  if (mode == 2) return ((const float*)mk)[i] != 0.0f;
  return ((const int*)mk)[i] != 0;
}

// ---- f32 weight -> bf16 staging ----
__global__ __launch_bounds__(256) void wconv_k(const float* __restrict__ src, u16* __restrict__ dst){
  long i = ((long)blockIdx.x * 256 + threadIdx.x) * 4;
  float4 v = *(const float4*)(src + i);
  u16x4 o; o.x = f2b(v.x); o.y = f2b(v.y); o.z = f2b(v.z); o.w = f2b(v.w);
  *(u16x4*)(dst + i) = o;
}

// ---- masked-patch select + f32->bf16 (full 4096 rows) ----
__global__ __launch_bounds__(256) void embed_k(const float* __restrict__ patches, const void* __restrict__ mask,
                                               const int* __restrict__ mode, const float* __restrict__ mtok,
                                               u16* __restrict__ MP){
  int row = blockIdx.x;
  bool m = mask_at(mask, *mode, row);
  int tid = threadIdx.x;
  long base = (long)row * 768;
  #pragma unroll
  for (int i = 0; i < 3; i++){
    int p = tid + i * 256;
    MP[base + p] = f2b(m ? mtok[p] : patches[base + p]);
  }
}

// ---- mask echo (output #2, f32 0/1) ----
__global__ __launch_bounds__(256) void maskout_k(const void* __restrict__ mask, const int* __restrict__ mode,
                                                 float* __restrict__ out){
  int i = blockIdx.x * 256 + threadIdx.x;
  out[i] = mask_at(mask, *mode, i) ? 1.0f : 0.0f;
}

// ---- layernorm over D=768 (bf16 in/out, f32 params+math) ----
__global__ __launch_bounds__(256) void ln_k(const u16* __restrict__ XR, u16* __restrict__ X,
                                            const float* __restrict__ s, const float* __restrict__ b){
  int row = blockIdx.x;
  int tid = threadIdx.x;
  const u16* xr = XR + (long)row * 768;
  float v0 = b2f(xr[tid]), v1 = b2f(xr[tid + 256]), v2 = b2f(xr[tid + 512]);
  float sum = v0 + v1 + v2, sq = v0 * v0 + v1 * v1 + v2 * v2;
  #pragma unroll
  for (int off = 32; off; off >>= 1){ sum += __shfl_xor(sum, off); sq += __shfl_xor(sq, off); }
  __shared__ float ls[4], lq[4];
  int wave = tid >> 6, lane = tid & 63;
  if (lane == 0){ ls[wave] = sum; lq[wave] = sq; }
  __syncthreads();
  sum = ls[0] + ls[1] + ls[2] + ls[3];
  sq  = lq[0] + lq[1] + lq[2] + lq[3];
  float mu = sum * (1.0f / 768.0f);
  float var = fmaxf(sq * (1.0f / 768.0f) - mu * mu, 0.0f);
  float rs = rsqrtf(var + 1e-5f);
  u16* xo = X + (long)row * 768;
  xo[tid]       = f2b((v0 - mu) * rs * s[tid]       + b[tid]);
  xo[tid + 256] = f2b((v1 - mu) * rs * s[tid + 256] + b[tid + 256]);
  xo[tid + 512] = f2b((v2 - mu) * rs * s[tid + 512] + b[tid + 512]);
}

// ---- generic bf16 MFMA GEMM: C = A[.,K] * W[N,K]^T (+ epilogue) ----
// 64x64 tile, 4 waves each 32x32, 3-stage pipelined K-loop (R2-proven).
// EPI: 0=qkv (QK natural ldc=1536, V -> VT per-head-transposed),
//      3=bias+resid, 4=bias+gelu, 5=bias -> f32 out, 6=bias+posemb
struct GP {
  const u16* A; const u16* W; u16* C; float* Cf;
  const float* bias; const float* pose;
  const u16* resid;
  u16* Cv;
  long sAz, sWz;
  int lda, ldw, ldc;
  int N, K;
  int wclamp, zBase;
};

template<int EPI>
__global__ __launch_bounds__(256)
void gemm_k(GP g){
  __shared__ __align__(16) u16 As[3][BM * BK];
  __shared__ __align__(16) u16 Bs[3][BN * BK];
  const int tid  = threadIdx.x;
  const int wave = tid >> 6, lane = tid & 63;
  const int quad = lane >> 4, l16 = lane & 15;
  const int wm = wave >> 1, wn = wave & 1;

  // bijective XCD-aware swizzle over the 2D (x,y) plane (m204)
  const int gx = gridDim.x;
  const int nwg = gx * gridDim.y;
  int bid = blockIdx.y * gx + blockIdx.x;
  {
    const int q = nwg >> 3, r = nwg & 7;
    const int xcd = bid & 7, loc = bid >> 3;
    bid = (xcd < r ? xcd * (q + 1) : r * (q + 1) + (xcd - r) * q) + loc;
  }
  const int m0 = (bid / gx) * BM;
  const int n0 = (bid % gx) * BN;
  const int z = blockIdx.z;

  const u16* Ab = g.A + (long)z * g.sAz;
  const u16* Wb = g.W + (long)z * g.sWz;

  f32x4 acc[2][2];
  #pragma unroll
  for (int i = 0; i < 2; i++)
    #pragma unroll
    for (int j = 0; j < 2; j++) acc[i][j] = (f32x4){0.f, 0.f, 0.f, 0.f};

  // staging: c0 = wave*64+lane in [0,256); row = c0>>2, 16B-slot = c0&3.
  // K-slot XOR swizzle (both sides): row stride 64B = 16 banks (alias
  // period 2 rows) -> XOR ((row>>1)&3). Verified 0-conflict in R3.
  const int c0 = wave * 64 + lane;
  const int arow = c0 >> 2, aslot = (c0 & 3) ^ ((arow >> 1) & 3);
  const u16* a0 = Ab + (long)(m0 + arow) * g.lda + aslot * 8;
  const u16* w0 = Wb + (long)min(n0 + arow, g.wclamp) * g.ldw + aslot * 8;
  const int o0 = wave * 512;  // u16 elems into stage (wave*1024 bytes)

  const int nt = g.K / BK;
  const int rs = (quad ^ ((l16 >> 1) & 3)) * 8;  // read slot (elems)

  #define STAGE(sb, kt) do { \
    __builtin_amdgcn_global_load_lds(GPTR(a0 + (kt)), LPTR(&As[(sb)][o0]), 16, 0, 0); \
    __builtin_amdgcn_global_load_lds(GPTR(w0 + (kt)), LPTR(&Bs[(sb)][o0]), 16, 0, 0); \
  } while (0)

  // prologue: fill stages 0 and 1; wait for tile 0 only (tile 1 in flight)
  STAGE(0, 0);
  if (nt > 1){
    STAGE(1, BK);
    asm volatile("s_waitcnt vmcnt(2)\n\ts_barrier" ::: "memory");
  } else {
    asm volatile("s_waitcnt vmcnt(0)\n\ts_barrier" ::: "memory");
  }

  int sC = 0, sP = 2;
  for (int t = 0; t < nt; ++t){
    if (t + 2 < nt) STAGE(sP, (t + 2) * BK);

    short8 af[2], bf[2];
    af[0] = *(const short8*)&As[sC][(wm * 32 + l16) * BK + rs];
    af[1] = *(const short8*)&As[sC][(wm * 32 + 16 + l16) * BK + rs];
    bf[0] = *(const short8*)&Bs[sC][(wn * 32 + l16) * BK + rs];
    bf[1] = *(const short8*)&Bs[sC][(wn * 32 + 16 + l16) * BK + rs];
    acc[0][0] = __builtin_amdgcn_mfma_f32_16x16x32_bf16(af[0], bf[0], acc[0][0], 0, 0, 0);
    acc[0][1] = __builtin_amdgcn_mfma_f32_16x16x32_bf16(af[0], bf[1], acc[0][1], 0, 0, 0);
    acc[1][0] = __builtin_amdgcn_mfma_f32_16x16x32_bf16(af[1], bf[0], acc[1][0], 0, 0, 0);
    acc[1][1] = __builtin_amdgcn_mfma_f32_16x16x32_bf16(af[1], bf[1], acc[1][1], 0, 0, 0);

    if (t + 2 < nt)      asm volatile("s_waitcnt vmcnt(2) lgkmcnt(0)\n\ts_barrier" ::: "memory");
    else if (t + 1 < nt) asm volatile("s_waitcnt vmcnt(0) lgkmcnt(0)\n\ts_barrier" ::: "memory");
    sC = (sC == 2) ? 0 : sC + 1;
    sP = (sP == 2) ? 0 : sP + 1;
  }
  #undef STAGE

  // epilogue: C/D layout col=lane&15, row=quad*4+reg
  #pragma unroll
  for (int i = 0; i < 2; i++){
    #pragma unroll
    for (int j = 0; j < 2; j++){
      #pragma unroll
      for (int rr = 0; rr < 4; rr++){
        const long r = (long)m0 + wm * 32 + i * 16 + quad * 4 + rr;
        const int  c = n0 + wn * 32 + j * 16 + l16;
        if (c >= g.N) continue;
        float v = acc[i][j][rr];
        if constexpr (EPI == 0){            // qkv: QK natural, V transposed per head
          u16 o = f2b(v + g.bias[c]);
          if (c < 1536) g.C[r * 1536 + c] = o;
          else {
            int c2 = c - 1536;
            int hh = ((int)(r >> 10)) * 12 + (c2 >> 6);
            g.Cv[((long)hh * 64 + (c2 & 63)) * 1024 + (r & 1023)] = o;
          }
        } else if constexpr (EPI == 3){     // bias + residual
          long o = r * (long)g.ldc + c;
          g.C[o] = f2b(v + g.bias[c] + b2f(g.resid[o]));
        } else if constexpr (EPI == 4){     // bias + exact gelu
          float t2 = v + g.bias[c];
          g.C[r * (long)g.ldc + c] = f2b(0.5f * t2 * (1.0f + erff(t2 * 0.70710678118654752f)));
        } else if constexpr (EPI == 5){     // bias -> f32 output (head)
          float t2 = v + g.bias[c];
          t2 = fminf(fmaxf(t2, -1.0e4f), 1.0e4f);
          g.Cf[r * (long)g.ldc + c] = t2;
        } else {                            // bias + pos_emb
          float val = v + g.bias[c] + g.pose[(long)(r & 1023) * 768 + c];
          g.C[r * (long)g.ldc + c] = f2b(val);
        }
      }
    }
  }
}

static inline void glaunch(int epi, dim3 grid, const GP& g, hipStream_t stream){
  switch (epi){
    case 0: gemm_k<0><<<grid, dim3(256), 0, stream>>>(g); break;
    case 3: gemm_k<3><<<grid, dim3(256), 0, stream>>>(g); break;
    case 4: gemm_k<4><<<grid, dim3(256), 0, stream>>>(g); break;
    case 5: gemm_k<5><<<grid, dim3(256), 0, stream>>>(g); break;
    default: gemm_k<6><<<grid, dim3(256), 0, stream>>>(g); break;
  }
}

// ---- fused flash attention: per block = one head (hhl) x one 64-row Q tile.
// QK[rows,1536]: Q cols h*64, K cols 768+h*64. VT[(hh)*64+d, k]. Online
// softmax over 16 kv-tiles of 64; S kept in f32 regs; P relayed via LDS in
// the gemm-verified swizzled layout; scale 0.125 + Swin rel-bias fused.
struct FP {
  const u16* QK; const u16* VT; u16* O; const float* relb;
  int oBase;   // batch offset for O rows (smallWs halves)
};

__global__ __launch_bounds__(256) void flash_k(FP f){
  __shared__ __align__(16) u16 Qs[2][2048];
  __shared__ __align__(16) u16 Ks[2][2][2048];
  __shared__ __align__(16) u16 Vs[2][2][2048];
  __shared__ __align__(16) u16 Ps[2][2048];
  __shared__ float rmx[64][2], rsm[64][2];
  const int tid  = threadIdx.x;
  const int wave = tid >> 6, lane = tid & 63;
  const int quad = lane >> 4, l16 = lane & 15;
  const int wm = wave >> 1, wn = wave & 1;
  const int hhl = blockIdx.y, bl = hhl / 12, h = hhl - bl * 12;
  const int q0 = blockIdx.x * 64;

  const int srow = tid >> 2, sslot = (tid & 3) ^ ((srow >> 1) & 3);
  const u16* Qsrc = f.QK + ((long)bl * 1024 + q0 + srow) * 1536 + h * 64 + sslot * 8;
  const u16* Ksrc = f.QK + ((long)bl * 1024 + srow) * 1536 + 768 + h * 64 + sslot * 8;
  const u16* Vsrc = f.VT + ((long)hhl * 64 + srow) * 1024 + sslot * 8;
  const int od = wave * 512;
  const int rs = (quad ^ ((l16 >> 1) & 3)) * 8;

  // prologue: Q (both k-halves) + K/V tile 0 into buf 0
  __builtin_amdgcn_global_load_lds(GPTR(Qsrc),      LPTR(&Qs[0][od]),    16, 0, 0);
  __builtin_amdgcn_global_load_lds(GPTR(Qsrc + 32), LPTR(&Qs[1][od]),    16, 0, 0);
  __builtin_amdgcn_global_load_lds(GPTR(Ksrc),      LPTR(&Ks[0][0][od]), 16, 0, 0);
  __builtin_amdgcn_global_load_lds(GPTR(Ksrc + 32), LPTR(&Ks[0][1][od]), 16, 0, 0);
  __builtin_amdgcn_global_load_lds(GPTR(Vsrc),      LPTR(&Vs[0][0][od]), 16, 0, 0);
  __builtin_amdgcn_global_load_lds(GPTR(Vsrc + 32), LPTR(&Vs[0][1][od]), 16, 0, 0);
  asm volatile("s_waitcnt vmcnt(0) lgkmcnt(0)\n\ts_barrier" ::: "memory");

  f32x4 Oa[2][2];
  #pragma unroll
  for (int i = 0; i < 2; i++)
    #pragma unroll
    for (int j = 0; j < 2; j++) Oa[i][j] = (f32x4){0.f, 0.f, 0.f, 0.f};
  float m_[2][4], l_[2][4];
  #pragma unroll
  for (int i = 0; i < 2; i++)
    #pragma unroll
    for (int rr = 0; rr < 4; rr++){ m_[i][rr] = -1e30f; l_[i][rr] = 0.0f; }

  for (int t = 0; t < 16; ++t){
    const int cur = t & 1;
    if (t < 15){
      const u16* kn = Ksrc + (long)(t + 1) * 98304;  // 64*1536
      const u16* vn = Vsrc + (t + 1) * 64;
      __builtin_amdgcn_global_load_lds(GPTR(kn),      LPTR(&Ks[cur ^ 1][0][od]), 16, 0, 0);
      __builtin_amdgcn_global_load_lds(GPTR(kn + 32), LPTR(&Ks[cur ^ 1][1][od]), 16, 0, 0);
      __builtin_amdgcn_global_load_lds(GPTR(vn),      LPTR(&Vs[cur ^ 1][0][od]), 16, 0, 0);
      __builtin_amdgcn_global_load_lds(GPTR(vn + 32), LPTR(&Vs[cur ^ 1][1][od]), 16, 0, 0);
    }

    // QK^T -> S (f32, 64x64 tile; this wave's 32x32 quadrant)
    f32x4 S[2][2];
    #pragma unroll
    for (int i = 0; i < 2; i++)
      #pragma unroll
      for (int j = 0; j < 2; j++) S[i][j] = (f32x4){0.f, 0.f, 0.f, 0.f};
    #pragma unroll
    for (int ks = 0; ks < 2; ks++){
      short8 af[2], bf[2];
      af[0] = *(const short8*)&Qs[ks][(wm * 32 + l16) * 32 + rs];
      af[1] = *(const short8*)&Qs[ks][(wm * 32 + 16 + l16) * 32 + rs];
      bf[0] = *(const short8*)&Ks[cur][ks][(wn * 32 + l16) * 32 + rs];
      bf[1] = *(const short8*)&Ks[cur][ks][(wn * 32 + 16 + l16) * 32 + rs];
      S[0][0] = __builtin_amdgcn_mfma_f32_16x16x32_bf16(af[0], bf[0], S[0][0], 0, 0, 0);
      S[0][1] = __builtin_amdgcn_mfma_f32_16x16x32_bf16(af[0], bf[1], S[0][1], 0, 0, 0);
      S[1][0] = __builtin_amdgcn_mfma_f32_16x16x32_bf16(af[1], bf[0], S[1][0], 0, 0, 0);
      S[1][1] = __builtin_amdgcn_mfma_f32_16x16x32_bf16(af[1], bf[1], S[1][1], 0, 0, 0);
    }

    // scale + rel-bias + per-row tile max (rows: quad*4+rr+i*16+wm*32)
    float tmax[2][4];
    #pragma unroll
    for (int i = 0; i < 2; i++)
      #pragma unroll
      for (int rr = 0; rr < 4; rr++) tmax[i][rr] = -1e30f;
    #pragma unroll
    for (int i = 0; i < 2; i++){
      #pragma unroll
      for (int j = 0; j < 2; j++){
        #pragma unroll
        for (int rr = 0; rr < 4; rr++){
          const int qy = wm * 32 + i * 16 + quad * 4 + rr;
          const int kx = t * 64 + wn * 32 + j * 16 + l16;
          const int ir = ((q0 + qy) >> 5) - (kx >> 5) + 31;
          const int ic = (qy & 31) - (kx & 31) + 31;
          float s = S[i][j][rr] * 0.125f + f.relb[ir * 63 + ic];
          S[i][j][rr] = s;
          tmax[i][rr] = fmaxf(tmax[i][rr], s);
        }
      }
    }
    #pragma unroll
    for (int i = 0; i < 2; i++)
      #pragma unroll
      for (int rr = 0; rr < 4; rr++)
        #pragma unroll
        for (int off = 1; off < 16; off <<= 1)
          tmax[i][rr] = fmaxf(tmax[i][rr], __shfl_xor(tmax[i][rr], off));
    if (l16 == 0){
      #pragma unroll
      for (int i = 0; i < 2; i++)
        #pragma unroll
        for (int rr = 0; rr < 4; rr++)
          rmx[wm * 32 + i * 16 + quad * 4 + rr][wn] = tmax[i][rr];
    }
    asm volatile("s_waitcnt lgkmcnt(0)\n\ts_barrier" ::: "memory");

    // online update: m_new, rescale O and l; P = exp(S - m_new) -> LDS bf16
    float psum[2][4];
    #pragma unroll
    for (int i = 0; i < 2; i++){
      #pragma unroll
      for (int rr = 0; rr < 4; rr++){
        const int row = wm * 32 + i * 16 + quad * 4 + rr;
        const float tm = fmaxf(rmx[row][0], rmx[row][1]);
        const float mn = fmaxf(m_[i][rr], tm);
        const float sc = __expf(m_[i][rr] - mn);
        m_[i][rr] = mn; l_[i][rr] *= sc;
        #pragma unroll
        for (int j = 0; j < 2; j++) Oa[i][j][rr] *= sc;
        psum[i][rr] = 0.0f;
      }
    }
    #pragma unroll
    for (int i = 0; i < 2; i++){
      #pragma unroll
      for (int j = 0; j < 2; j++){
        #pragma unroll
        for (int rr = 0; rr < 4; rr++){
          float p = __expf(S[i][j][rr] - m_[i][rr]);
          psum[i][rr] += p;
          const int row = wm * 32 + i * 16 + quad * 4 + rr;
          const int col = wn * 32 + j * 16 + l16;
          const int half = col >> 5, c5 = col & 31;
          const int ps = (c5 >> 3) ^ ((row >> 1) & 3);
          Ps[half][row * 32 + ps * 8 + (c5 & 7)] = f2b(p);
        }
      }
    }
    #pragma unroll
    for (int i = 0; i < 2; i++)
      #pragma unroll
      for (int rr = 0; rr < 4; rr++)
        #pragma unroll
        for (int off = 1; off < 16; off <<= 1)
          psum[i][rr] += __shfl_xor(psum[i][rr], off);
    if (l16 == 0){
      #pragma unroll
      for (int i = 0; i < 2; i++)
        #pragma unroll
        for (int rr = 0; rr < 4; rr++)
          rsm[wm * 32 + i * 16 + quad * 4 + rr][wn] = psum[i][rr];
    }
    asm volatile("s_waitcnt lgkmcnt(0)\n\ts_barrier" ::: "memory");
    #pragma unroll
    for (int i = 0; i < 2; i++)
      #pragma unroll
      for (int rr = 0; rr < 4; rr++){
        const int row = wm * 32 + i * 16 + quad * 4 + rr;
        l_[i][rr] += rsm[row][0] + rsm[row][1];
      }

    // PV: O += P[64q,64k] * V[64k,64d]  (B operand = VT rows d)
    #pragma unroll
    for (int ks = 0; ks < 2; ks++){
      short8 pa[2], bv[2];
      pa[0] = *(const short8*)&Ps[ks][(wm * 32 + l16) * 32 + rs];
      pa[1] = *(const short8*)&Ps[ks][(wm * 32 + 16 + l16) * 32 + rs];
      bv[0] = *(const short8*)&Vs[cur][ks][(wn * 32 + l16) * 32 + rs];
      bv[1] = *(const short8*)&Vs[cur][ks][(wn * 32 + 16 + l16) * 32 + rs];
      Oa[0][0] = __builtin_amdgcn_mfma_f32_16x16x32_bf16(pa[0], bv[0], Oa[0][0], 0, 0, 0);
      Oa[0][1] = __builtin_amdgcn_mfma_f32_16x16x32_bf16(pa[0], bv[1], Oa[0][1], 0, 0, 0);
      Oa[1][0] = __builtin_amdgcn_mfma_f32_16x16x32_bf16(pa[1], bv[0], Oa[1][0], 0, 0, 0);
      Oa[1][1] = __builtin_amdgcn_mfma_f32_16x16x32_bf16(pa[1], bv[1], Oa[1][1], 0, 0, 0);
    }
    if (t < 15) asm volatile("s_waitcnt vmcnt(0) lgkmcnt(0)\n\ts_barrier" ::: "memory");
  }

  // epilogue: O /= l -> bf16 O[(oBase+bl)*1024 + q0+row][h*64 + col]
  #pragma unroll
  for (int i = 0; i < 2; i++){
    #pragma unroll
    for (int rr = 0; rr < 4; rr++){
      const float inv = 1.0f / l_[i][rr];
      const int row = wm * 32 + i * 16 + quad * 4 + rr;
      const long ro = ((long)(f.oBase + bl) * 1024 + q0 + row) * 768 + h * 64;
      #pragma unroll
      for (int j = 0; j < 2; j++)
        f.O[ro + wn * 32 + j * 16 + l16] = f2b(Oa[i][j][rr] * inv);
    }
  }
}

extern "C" void kernel_launch(void* const* d_in, const int* in_sizes, int n_in,
                              void* d_out, int out_size, void* d_ws, size_t ws_size,
                              hipStream_t stream){
  (void)in_sizes; (void)n_in; (void)out_size;
  const float* patches = (const float*)d_in[0];
  const void*  mask    = d_in[1];
  const float* mtok    = (const float*)d_in[2];
  const float* patch_w = (const float*)d_in[3];
  const float* patch_b = (const float*)d_in[4];
  const float* pos_emb = (const float*)d_in[5];
  const float* rel_b   = (const float*)d_in[6];
  const float* in_w    = (const float*)d_in[7];
  const float* in_b    = (const float*)d_in[8];
  const float* attn_ow = (const float*)d_in[9];
  const float* attn_ob = (const float*)d_in[10];
  const float* ln1_s   = (const float*)d_in[11];
  const float* ln1_b   = (const float*)d_in[12];
  const float* ffn_w1  = (const float*)d_in[13];
  const float* ffn_b1  = (const float*)d_in[14];
  const float* ffn_w2  = (const float*)d_in[15];
  const float* ffn_b2  = (const float*)d_in[16];
  const float* ln2_s   = (const float*)d_in[17];
  const float* ln2_b   = (const float*)d_in[18];
  const float* head_w  = (const float*)d_in[19];
  const float* head_b  = (const float*)d_in[20];

  // ws base layout (known safe)
  char* ws = (char*)d_ws;
  int* mode = (int*)ws;
  u16* X  = (u16*)(ws + 256);            // [4096,768]
  u16* WA = X + 3145728;                 // up to [3072,768]
  u16* WB = WA + 2359296;                // up to [3072,768]
  char* EX = (char*)(WB + 2359296);      // extra region
  long extra = (long)ws_size - 15728896L;
  const bool bigWs = extra >= 25165824L; // QK+VT+O (= H) fits in ws extra

  u16*   dout16 = (u16*)d_out;
  float* doutf  = (float*)d_out;

  // big-ws pointers (attention phase)
  u16* QKp = (u16*)EX;                   // [4096,1536]
  u16* VTp = QKp + 6291456;              // [48*64,1024]
  u16* Op  = VTp + 3145728;              // [4096,768]
  u16* Hp  = (u16*)EX;                   // [4096,3072] (ffn phase, aliased)
  // small-ws pointers: attention staged in d_out halves
  u16* O16  = dout16;                    // [4096,768]
  u16* QKh  = dout16 + 3145728;          // [2048,1536]
  u16* VTh  = dout16 + 6291456;          // [24*64,1024]
  u16* XRb  = dout16 + 3145728;          // [4096,768] (after QKh/VTh dead)
  u16* Hc   = dout16;                    // [2048,3072]
  u16* XRc  = dout16 + 6291456;          // [2048,768]

  detect_k<<<dim3(1), dim3(256), 0, stream>>>((const u16*)mask, mode);

  GP g; FP fp;
  // embed (MP in d_out) + patch projection -> X
  wconv_k<<<dim3(576), dim3(256), 0, stream>>>(patch_w, WA);
  embed_k<<<dim3(4096), dim3(256), 0, stream>>>(patches, mask, mode, mtok, dout16);
  g = {};
  g.A = dout16; g.lda = 768; g.W = WA; g.ldw = 768; g.wclamp = 767;
  g.C = X; g.ldc = 768; g.N = 768; g.K = 768;
  g.bias = patch_b; g.pose = pos_emb;
  glaunch(6, dim3(12, 64, 1), g, stream);

  for (int l = 0; l < 6; l++){
    wconv_k<<<dim3(1728), dim3(256), 0, stream>>>(in_w + (long)l * 1769472, WA);
    wconv_k<<<dim3(576),  dim3(256), 0, stream>>>(attn_ow + (long)l * 589824, WB);

    if (bigWs){
      // qkv full-M
      g = {};
      g.A = X; g.lda = 768; g.W = WA; g.ldw = 768; g.wclamp = 2303;
      g.bias = in_b + (long)l * 2304;
      g.C = QKp; g.Cv = VTp; g.N = 2304; g.K = 768;
      glaunch(0, dim3(36, 64, 1), g, stream);

      fp = {};
      fp.QK = QKp; fp.VT = VTp; fp.O = Op; fp.relb = rel_b; fp.oBase = 0;
      flash_k<<<dim3(16, 48), dim3(256), 0, stream>>>(fp);

      // o-proj + residual -> XR(d_out), LN1 -> X
      g = {};
      g.A = Op; g.lda = 768; g.W = WB; g.ldw = 768; g.wclamp = 767;
      g.bias = attn_ob + (long)l * 768; g.resid = X;
      g.C = dout16; g.ldc = 768; g.N = 768; g.K = 768;
      glaunch(3, dim3(12, 64, 1), g, stream);
      ln_k<<<dim3(4096), dim3(256), 0, stream>>>(dout16, X, ln1_s + l * 768, ln1_b + l * 768);
    } else {
      for (int hb = 0; hb < 2; hb++){
        g = {};
        g.A = X + (long)hb * 1572864; g.lda = 768;
        g.W = WA; g.ldw = 768; g.wclamp = 2303;
        g.bias = in_b + (long)l * 2304;
        g.C = QKh; g.Cv = VTh; g.N = 2304; g.K = 768;
        glaunch(0, dim3(36, 32, 1), g, stream);

        fp = {};
        fp.QK = QKh; fp.VT = VTh; fp.O = O16; fp.relb = rel_b; fp.oBase = hb * 2;
        flash_k<<<dim3(16, 24), dim3(256), 0, stream>>>(fp);
      }
      g = {};
      g.A = O16; g.lda = 768; g.W = WB; g.ldw = 768; g.wclamp = 767;
      g.bias = attn_ob + (long)l * 768; g.resid = X;
      g.C = XRb; g.ldc = 768; g.N = 768; g.K = 768;
      glaunch(3, dim3(12, 64, 1), g, stream);
      ln_k<<<dim3(4096), dim3(256), 0, stream>>>(XRb, X, ln1_s + l * 768, ln1_b + l * 768);
    }

    wconv_k<<<dim3(2304), dim3(256), 0, stream>>>(ffn_w1 + (long)l * 2359296, WA);
    wconv_k<<<dim3(2304), dim3(256), 0, stream>>>(ffn_w2 + (long)l * 2359296, WB);

    if (bigWs){
      g = {};
      g.A = X; g.lda = 768; g.W = WA; g.ldw = 768; g.wclamp = 3071;
      g.bias = ffn_b1 + (long)l * 3072;
      g.C = Hp; g.ldc = 3072; g.N = 3072; g.K = 768;
      glaunch(4, dim3(48, 64, 1), g, stream);
      g = {};
      g.A = Hp; g.lda = 3072; g.W = WB; g.ldw = 3072; g.wclamp = 767;
      g.bias = ffn_b2 + (long)l * 768; g.resid = X;
      g.C = dout16; g.ldc = 768; g.N = 768; g.K = 3072;
      glaunch(3, dim3(12, 64, 1), g, stream);
      ln_k<<<dim3(4096), dim3(256), 0, stream>>>(dout16, X, ln2_s + l * 768, ln2_b + l * 768);
    } else {
      for (int cc = 0; cc < 2; cc++){
        u16* Xc = X + (long)cc * 1572864;
        g = {};
        g.A = Xc; g.lda = 768; g.W = WA; g.ldw = 768; g.wclamp = 3071;
        g.bias = ffn_b1 + (long)l * 3072;
        g.C = Hc; g.ldc = 3072; g.N = 3072; g.K = 768;
        glaunch(4, dim3(48, 32, 1), g, stream);
        g = {};
        g.A = Hc; g.lda = 3072; g.W = WB; g.ldw = 3072; g.wclamp = 767;
        g.bias = ffn_b2 + (long)l * 768; g.resid = Xc;
        g.C = XRc; g.ldc = 768; g.N = 768; g.K = 3072;
        glaunch(3, dim3(12, 32, 1), g, stream);
        ln_k<<<dim3(2048), dim3(256), 0, stream>>>(XRc, Xc, ln2_s + l * 768, ln2_b + l * 768);
      }
    }
  }

  // head: logits (f32) -> d_out
  wconv_k<<<dim3(768), dim3(256), 0, stream>>>(head_w, WA);
  g = {};
  g.A = X; g.lda = 768; g.W = WA; g.ldw = 768; g.wclamp = 1023;
  g.bias = head_b;
  g.Cf = doutf; g.ldc = 1024; g.N = 1024; g.K = 768;
  glaunch(5, dim3(16, 64, 1), g, stream);
  maskout_k<<<dim3(16), dim3(256), 0, stream>>>(mask, mode, doutf + 4194304);
}

// Round 5
// 1646.592 us; speedup vs baseline: 1.2388x; 1.1268x over previous
//
#include <hip/hip_runtime.h>
#include <hip/hip_bf16.h>
#include <stdint.h>

// StackedContextViT forward, MI355X gfx950. ALL inputs/outputs are FLOAT32.
// Internal: bf16 storage + bf16 MFMA, f32 accumulate, f32 epilogue math.
// B=4 N=1024 PD=768 D=768 H=12 HD=64 L=6 F=3072 V=1024 G=32
// ws base (known safe, 15.73MB): [0]mode | X bf16[4096,768] | WA | WB
// ws extra (if >=25.2MB): QK[4096,1536] | VT[48*64,1024] | O[4096,768]  (attn)
//                         H[4096,3072]                                  (ffn, aliased)
// d_out (16.79MB) is scratch until the head GEMM writes f32 logits.
//
// R5: flash_k rewritten in TRANSPOSED score layout (S^T = mfma(K,Q)):
//     lane holds 2 q-cols x 8 k-vals -> row-softmax is in-lane + 2 shfl;
//     P relayout = cvt_pk_bf16_f32 pairs + ds_write_b64 (4 consecutive k);
//     PV = mfma(V^T, P) -> O^T, epilogue packs 4 consecutive d / store;
//     rel-bias fetched as one dwordx4 (4 consecutive ic per rr-group).
//     + m204 XCD swizzle on the flash grid (q-tiles of a head share XCD).
//     R4 post-mortem: flash was VALU-bound (VALUBusy 48%, Mfma 6%) on
//     softmax plumbing; this cuts ~40-50% of per-tile VALU inst.

#define BM 64
#define BN 64
#define BK 32

using u16 = unsigned short;
typedef __attribute__((ext_vector_type(8))) short short8;
typedef __attribute__((ext_vector_type(4))) float f32x4;
typedef __attribute__((ext_vector_type(4))) u16 u16x4;
typedef float f32x4u __attribute__((ext_vector_type(4), aligned(4)));

#define GPTR(p) ((const __attribute__((address_space(1))) void*)(p))
#define LPTR(p) ((__attribute__((address_space(3))) void*)(p))

__device__ __forceinline__ float b2f(u16 u){
  union { unsigned int i; float f; } x; x.i = ((unsigned int)u) << 16; return x.f;
}
__device__ __forceinline__ u16 f2b(float f){
  f = fminf(fmaxf(f, -448.0f), 448.0f);
  union { float f; unsigned int i; } x; x.f = f;
  unsigned int r = x.i + 0x7FFFu + ((x.i >> 16) & 1u);
  return (u16)(r >> 16);
}
__device__ __forceinline__ unsigned int cvtpk(float lo, float hi){
  unsigned int r;
  asm("v_cvt_pk_bf16_f32 %0, %1, %2" : "=v"(r) : "v"(lo), "v"(hi));
  return r;
}

// ---- mask dtype detection: 0=u8 bool, 1=bf16, 2=f32, 3=i32 ----
__global__ __launch_bounds__(256) void detect_k(const u16* __restrict__ mk, int* __restrict__ mode){
  __shared__ int f[3];
  int tid = threadIdx.x;
  if (tid < 3) f[tid] = 0;
  __syncthreads();
  for (int i = tid; i < 2048; i += 256){
    u16 u = mk[i];
    if (u == 256 || u == 257) atomicOr(&f[0], 1);
    if (u == 0x3F80){ if ((i & 1) == 0) atomicOr(&f[1], 1); else atomicOr(&f[2], 1); }
  }
  __syncthreads();
  if (tid == 0){
    int m;
    if (f[0]) m = 0;
    else if (f[1]) m = 1;
    else if (f[2]) m = 2;
    else m = 3;
    *mode = m;
  }
}

__device__ __forceinline__ bool mask_at(const void* mk, int mode, int i){
  if (mode == 0) return ((const unsigned char*)mk)[i] != 0;
  if (mode == 1) return ((const u16*)mk)[i] != 0;
  if (mode == 2) return ((const float*)mk)[i] != 0.0f;
  return ((const int*)mk)[i] != 0;
}

// ---- f32 weight -> bf16 staging ----
__global__ __launch_bounds__(256) void wconv_k(const float* __restrict__ src, u16* __restrict__ dst){
  long i = ((long)blockIdx.x * 256 + threadIdx.x) * 4;
  float4 v = *(const float4*)(src + i);
  u16x4 o; o.x = f2b(v.x); o.y = f2b(v.y); o.z = f2b(v.z); o.w = f2b(v.w);
  *(u16x4*)(dst + i) = o;
}

// ---- masked-patch select + f32->bf16 (full 4096 rows) ----
__global__ __launch_bounds__(256) void embed_k(const float* __restrict__ patches, const void* __restrict__ mask,
                                               const int* __restrict__ mode, const float* __restrict__ mtok,
                                               u16* __restrict__ MP){
  int row = blockIdx.x;
  bool m = mask_at(mask, *mode, row);
  int tid = threadIdx.x;
  long base = (long)row * 768;
  #pragma unroll
  for (int i = 0; i < 3; i++){
    int p = tid + i * 256;
    MP[base + p] = f2b(m ? mtok[p] : patches[base + p]);
  }
}

// ---- mask echo (output #2, f32 0/1) ----
__global__ __launch_bounds__(256) void maskout_k(const void* __restrict__ mask, const int* __restrict__ mode,
                                                 float* __restrict__ out){
  int i = blockIdx.x * 256 + threadIdx.x;
  out[i] = mask_at(mask, *mode, i) ? 1.0f : 0.0f;
}

// ---- layernorm over D=768 (bf16 in/out, f32 params+math) ----
__global__ __launch_bounds__(256) void ln_k(const u16* __restrict__ XR, u16* __restrict__ X,
                                            const float* __restrict__ s, const float* __restrict__ b){
  int row = blockIdx.x;
  int tid = threadIdx.x;
  const u16* xr = XR + (long)row * 768;
  float v0 = b2f(xr[tid]), v1 = b2f(xr[tid + 256]), v2 = b2f(xr[tid + 512]);
  float sum = v0 + v1 + v2, sq = v0 * v0 + v1 * v1 + v2 * v2;
  #pragma unroll
  for (int off = 32; off; off >>= 1){ sum += __shfl_xor(sum, off); sq += __shfl_xor(sq, off); }
  __shared__ float ls[4], lq[4];
  int wave = tid >> 6, lane = tid & 63;
  if (lane == 0){ ls[wave] = sum; lq[wave] = sq; }
  __syncthreads();
  sum = ls[0] + ls[1] + ls[2] + ls[3];
  sq  = lq[0] + lq[1] + lq[2] + lq[3];
  float mu = sum * (1.0f / 768.0f);
  float var = fmaxf(sq * (1.0f / 768.0f) - mu * mu, 0.0f);
  float rs = rsqrtf(var + 1e-5f);
  u16* xo = X + (long)row * 768;
  xo[tid]       = f2b((v0 - mu) * rs * s[tid]       + b[tid]);
  xo[tid + 256] = f2b((v1 - mu) * rs * s[tid + 256] + b[tid + 256]);
  xo[tid + 512] = f2b((v2 - mu) * rs * s[tid + 512] + b[tid + 512]);
}

// ---- generic bf16 MFMA GEMM: C = A[.,K] * W[N,K]^T (+ epilogue) ----
// 64x64 tile, 4 waves each 32x32, 3-stage pipelined K-loop (R2-proven).
struct GP {
  const u16* A; const u16* W; u16* C; float* Cf;
  const float* bias; const float* pose;
  const u16* resid;
  u16* Cv;
  long sAz, sWz;
  int lda, ldw, ldc;
  int N, K;
  int wclamp, zBase;
};

template<int EPI>
__global__ __launch_bounds__(256)
void gemm_k(GP g){
  __shared__ __align__(16) u16 As[3][BM * BK];
  __shared__ __align__(16) u16 Bs[3][BN * BK];
  const int tid  = threadIdx.x;
  const int wave = tid >> 6, lane = tid & 63;
  const int quad = lane >> 4, l16 = lane & 15;
  const int wm = wave >> 1, wn = wave & 1;

  // bijective XCD-aware swizzle over the 2D (x,y) plane (m204)
  const int gx = gridDim.x;
  const int nwg = gx * gridDim.y;
  int bid = blockIdx.y * gx + blockIdx.x;
  {
    const int q = nwg >> 3, r = nwg & 7;
    const int xcd = bid & 7, loc = bid >> 3;
    bid = (xcd < r ? xcd * (q + 1) : r * (q + 1) + (xcd - r) * q) + loc;
  }
  const int m0 = (bid / gx) * BM;
  const int n0 = (bid % gx) * BN;
  const int z = blockIdx.z;

  const u16* Ab = g.A + (long)z * g.sAz;
  const u16* Wb = g.W + (long)z * g.sWz;

  f32x4 acc[2][2];
  #pragma unroll
  for (int i = 0; i < 2; i++)
    #pragma unroll
    for (int j = 0; j < 2; j++) acc[i][j] = (f32x4){0.f, 0.f, 0.f, 0.f};

  // K-slot XOR swizzle (both sides): row stride 64B = 16 banks (alias
  // period 2 rows) -> XOR ((row>>1)&3). Verified 0-conflict in R3.
  const int c0 = wave * 64 + lane;
  const int arow = c0 >> 2, aslot = (c0 & 3) ^ ((arow >> 1) & 3);
  const u16* a0 = Ab + (long)(m0 + arow) * g.lda + aslot * 8;
  const u16* w0 = Wb + (long)min(n0 + arow, g.wclamp) * g.ldw + aslot * 8;
  const int o0 = wave * 512;

  const int nt = g.K / BK;
  const int rs = (quad ^ ((l16 >> 1) & 3)) * 8;

  #define STAGE(sb, kt) do { \
    __builtin_amdgcn_global_load_lds(GPTR(a0 + (kt)), LPTR(&As[(sb)][o0]), 16, 0, 0); \
    __builtin_amdgcn_global_load_lds(GPTR(w0 + (kt)), LPTR(&Bs[(sb)][o0]), 16, 0, 0); \
  } while (0)

  STAGE(0, 0);
  if (nt > 1){
    STAGE(1, BK);
    asm volatile("s_waitcnt vmcnt(2)\n\ts_barrier" ::: "memory");
  } else {
    asm volatile("s_waitcnt vmcnt(0)\n\ts_barrier" ::: "memory");
  }

  int sC = 0, sP = 2;
  for (int t = 0; t < nt; ++t){
    if (t + 2 < nt) STAGE(sP, (t + 2) * BK);

    short8 af[2], bf[2];
    af[0] = *(const short8*)&As[sC][(wm * 32 + l16) * BK + rs];
    af[1] = *(const short8*)&As[sC][(wm * 32 + 16 + l16) * BK + rs];
    bf[0] = *(const short8*)&Bs[sC][(wn * 32 + l16) * BK + rs];
    bf[1] = *(const short8*)&Bs[sC][(wn * 32 + 16 + l16) * BK + rs];
    acc[0][0] = __builtin_amdgcn_mfma_f32_16x16x32_bf16(af[0], bf[0], acc[0][0], 0, 0, 0);
    acc[0][1] = __builtin_amdgcn_mfma_f32_16x16x32_bf16(af[0], bf[1], acc[0][1], 0, 0, 0);
    acc[1][0] = __builtin_amdgcn_mfma_f32_16x16x32_bf16(af[1], bf[0], acc[1][0], 0, 0, 0);
    acc[1][1] = __builtin_amdgcn_mfma_f32_16x16x32_bf16(af[1], bf[1], acc[1][1], 0, 0, 0);

    if (t + 2 < nt)      asm volatile("s_waitcnt vmcnt(2) lgkmcnt(0)\n\ts_barrier" ::: "memory");
    else if (t + 1 < nt) asm volatile("s_waitcnt vmcnt(0) lgkmcnt(0)\n\ts_barrier" ::: "memory");
    sC = (sC == 2) ? 0 : sC + 1;
    sP = (sP == 2) ? 0 : sP + 1;
  }
  #undef STAGE

  // epilogue: C/D layout col=lane&15, row=quad*4+reg
  #pragma unroll
  for (int i = 0; i < 2; i++){
    #pragma unroll
    for (int j = 0; j < 2; j++){
      #pragma unroll
      for (int rr = 0; rr < 4; rr++){
        const long r = (long)m0 + wm * 32 + i * 16 + quad * 4 + rr;
        const int  c = n0 + wn * 32 + j * 16 + l16;
        if (c >= g.N) continue;
        float v = acc[i][j][rr];
        if constexpr (EPI == 0){            // qkv: QK natural, V transposed per head
          u16 o = f2b(v + g.bias[c]);
          if (c < 1536) g.C[r * 1536 + c] = o;
          else {
            int c2 = c - 1536;
            int hh = ((int)(r >> 10)) * 12 + (c2 >> 6);
            g.Cv[((long)hh * 64 + (c2 & 63)) * 1024 + (r & 1023)] = o;
          }
        } else if constexpr (EPI == 3){     // bias + residual
          long o = r * (long)g.ldc + c;
          g.C[o] = f2b(v + g.bias[c] + b2f(g.resid[o]));
        } else if constexpr (EPI == 4){     // bias + exact gelu
          float t2 = v + g.bias[c];
          g.C[r * (long)g.ldc + c] = f2b(0.5f * t2 * (1.0f + erff(t2 * 0.70710678118654752f)));
        } else if constexpr (EPI == 5){     // bias -> f32 output (head)
          float t2 = v + g.bias[c];
          t2 = fminf(fmaxf(t2, -1.0e4f), 1.0e4f);
          g.Cf[r * (long)g.ldc + c] = t2;
        } else {                            // bias + pos_emb
          float val = v + g.bias[c] + g.pose[(long)(r & 1023) * 768 + c];
          g.C[r * (long)g.ldc + c] = f2b(val);
        }
      }
    }
  }
}

static inline void glaunch(int epi, dim3 grid, const GP& g, hipStream_t stream){
  switch (epi){
    case 0: gemm_k<0><<<grid, dim3(256), 0, stream>>>(g); break;
    case 3: gemm_k<3><<<grid, dim3(256), 0, stream>>>(g); break;
    case 4: gemm_k<4><<<grid, dim3(256), 0, stream>>>(g); break;
    case 5: gemm_k<5><<<grid, dim3(256), 0, stream>>>(g); break;
    default: gemm_k<6><<<grid, dim3(256), 0, stream>>>(g); break;
  }
}

// ---- fused flash attention, TRANSPOSED layout ----
// Per block: one head (hhl) x one 64-row Q tile. S^T = mfma(K,Q): lane holds
// 2 q-cols (qloc0/1) x 8 k-vals (i x rr, quads give k 4-blocks). Online
// softmax state (m,l) is 2 scalars/lane. P stored [q][k] via cvt_pk+b64.
// PV: O^T = mfma(V^T, P). Swizzle/fragment patterns identical to gemm_k.
struct FP {
  const u16* QK; const u16* VT; u16* O; const float* relb;
  int oBase;
};

__global__ __launch_bounds__(256) void flash_k(FP f){
  __shared__ __align__(16) u16 Qs[2][2048];
  __shared__ __align__(16) u16 Ks[2][2][2048];
  __shared__ __align__(16) u16 Vs[2][2][2048];
  __shared__ __align__(16) u16 Ps[2][2048];
  __shared__ float rmx[64][2], rsm[64][2];
  const int tid  = threadIdx.x;
  const int wave = tid >> 6, lane = tid & 63;
  const int quad = lane >> 4, l16 = lane & 15;
  const int wm = wave >> 1, wn = wave & 1;

  // m204 bijective XCD swizzle: q-tiles of one head stay on one XCD
  {
  }
  const int nwg = gridDim.x * gridDim.y;
  int orig = blockIdx.y * gridDim.x + blockIdx.x;
  const int q_ = nwg >> 3, r_ = nwg & 7;
  const int xcd = orig & 7, loc = orig >> 3;
  const int nid = (xcd < r_ ? xcd * (q_ + 1) : r_ * (q_ + 1) + (xcd - r_) * q_) + loc;
  const int hhl = nid >> 4;          // gridDim.x == 16
  const int q0  = (nid & 15) * 64;
  const int bl = hhl / 12, h = hhl - bl * 12;

  const int srow = tid >> 2, sslot = (tid & 3) ^ ((srow >> 1) & 3);
  const u16* Qsrc = f.QK + ((long)bl * 1024 + q0 + srow) * 1536 + h * 64 + sslot * 8;
  const u16* Ksrc = f.QK + ((long)bl * 1024 + srow) * 1536 + 768 + h * 64 + sslot * 8;
  const u16* Vsrc = f.VT + ((long)hhl * 64 + srow) * 1024 + sslot * 8;
  const int od = wave * 512;
  const int rs = (quad ^ ((l16 >> 1) & 3)) * 8;

  // prologue: Q (both d-halves) + K/V tile 0 into buf 0
  __builtin_amdgcn_global_load_lds(GPTR(Qsrc),      LPTR(&Qs[0][od]),    16, 0, 0);
  __builtin_amdgcn_global_load_lds(GPTR(Qsrc + 32), LPTR(&Qs[1][od]),    16, 0, 0);
  __builtin_amdgcn_global_load_lds(GPTR(Ksrc),      LPTR(&Ks[0][0][od]), 16, 0, 0);
  __builtin_amdgcn_global_load_lds(GPTR(Ksrc + 32), LPTR(&Ks[0][1][od]), 16, 0, 0);
  __builtin_amdgcn_global_load_lds(GPTR(Vsrc),      LPTR(&Vs[0][0][od]), 16, 0, 0);
  __builtin_amdgcn_global_load_lds(GPTR(Vsrc + 32), LPTR(&Vs[0][1][od]), 16, 0, 0);
  asm volatile("s_waitcnt vmcnt(0) lgkmcnt(0)\n\ts_barrier" ::: "memory");

  f32x4 Oa[2][2];      // [i: d-block][j: q-block], O^T accumulator
  #pragma unroll
  for (int i = 0; i < 2; i++)
    #pragma unroll
    for (int j = 0; j < 2; j++) Oa[i][j] = (f32x4){0.f, 0.f, 0.f, 0.f};
  float m_[2] = {-1e30f, -1e30f}, l_[2] = {0.0f, 0.0f};

  const int qloc0 = wn * 32 + l16, qloc1 = qloc0 + 16;
  const int qr = (q0 >> 5) + wn;
  const float* brbase = f.relb + (long)(qr - wm + 31) * 63;
  int ic3[2][2];   // column offset (already -3 for the dwordx4 trick)
  #pragma unroll
  for (int i = 0; i < 2; i++)
    #pragma unroll
    for (int j = 0; j < 2; j++)
      ic3[i][j] = (j * 16 + l16) - (i * 16 + quad * 4) + 28;

  for (int t = 0; t < 16; ++t){
    const int cur = t & 1;
    if (t < 15){
      const u16* kn = Ksrc + (long)(t + 1) * 98304;  // 64*1536
      const u16* vn = Vsrc + (t + 1) * 64;
      __builtin_amdgcn_global_load_lds(GPTR(kn),      LPTR(&Ks[cur ^ 1][0][od]), 16, 0, 0);
      __builtin_amdgcn_global_load_lds(GPTR(kn + 32), LPTR(&Ks[cur ^ 1][1][od]), 16, 0, 0);
      __builtin_amdgcn_global_load_lds(GPTR(vn),      LPTR(&Vs[cur ^ 1][0][od]), 16, 0, 0);
      __builtin_amdgcn_global_load_lds(GPTR(vn + 32), LPTR(&Vs[cur ^ 1][1][od]), 16, 0, 0);
    }

    // S^T = K Q^T (A = K rows k, B = Q rows q)
    f32x4 ST[2][2];
    #pragma unroll
    for (int i = 0; i < 2; i++)
      #pragma unroll
      for (int j = 0; j < 2; j++) ST[i][j] = (f32x4){0.f, 0.f, 0.f, 0.f};
    #pragma unroll
    for (int ds = 0; ds < 2; ds++){
      short8 kf[2], qf[2];
      kf[0] = *(const short8*)&Ks[cur][ds][(wm * 32 + l16) * 32 + rs];
      kf[1] = *(const short8*)&Ks[cur][ds][(wm * 32 + 16 + l16) * 32 + rs];
      qf[0] = *(const short8*)&Qs[ds][(wn * 32 + l16) * 32 + rs];
      qf[1] = *(const short8*)&Qs[ds][(wn * 32 + 16 + l16) * 32 + rs];
      ST[0][0] = __builtin_amdgcn_mfma_f32_16x16x32_bf16(kf[0], qf[0], ST[0][0], 0, 0, 0);
      ST[0][1] = __builtin_amdgcn_mfma_f32_16x16x32_bf16(kf[0], qf[1], ST[0][1], 0, 0, 0);
      ST[1][0] = __builtin_amdgcn_mfma_f32_16x16x32_bf16(kf[1], qf[0], ST[1][0], 0, 0, 0);
      ST[1][1] = __builtin_amdgcn_mfma_f32_16x16x32_bf16(kf[1], qf[1], ST[1][1], 0, 0, 0);
    }

    // scale + Swin rel-bias (one dwordx4 per (i,j); bv[3-rr] = bias(rr)),
    // per-q tile max: in-lane over 8 k + quad butterfly (xor 16,32)
    const float* br = brbase - (long)(2 * t) * 63;
    float s[2][2][4];
    float tmax0 = -1e30f, tmax1 = -1e30f;
    #pragma unroll
    for (int i = 0; i < 2; i++){
      #pragma unroll
      for (int j = 0; j < 2; j++){
        f32x4u bv = *(const f32x4u*)(br + ic3[i][j]);
        #pragma unroll
        for (int rr = 0; rr < 4; rr++){
          float sv = ST[i][j][rr] * 0.125f + bv[3 - rr];
          s[i][j][rr] = sv;
          if (j == 0) tmax0 = fmaxf(tmax0, sv); else tmax1 = fmaxf(tmax1, sv);
        }
      }
    }
    tmax0 = fmaxf(tmax0, __shfl_xor(tmax0, 16));
    tmax0 = fmaxf(tmax0, __shfl_xor(tmax0, 32));
    tmax1 = fmaxf(tmax1, __shfl_xor(tmax1, 16));
    tmax1 = fmaxf(tmax1, __shfl_xor(tmax1, 32));
    if (quad == 0){ rmx[qloc0][wm] = tmax0; rmx[qloc1][wm] = tmax1; }
    asm volatile("s_waitcnt lgkmcnt(0)\n\ts_barrier" ::: "memory");

    // online update (2 scalars/lane)
    float sc0, sc1;
    {
      float mn = fmaxf(m_[0], fmaxf(rmx[qloc0][0], rmx[qloc0][1]));
      sc0 = __expf(m_[0] - mn); m_[0] = mn;
    }
    {
      float mn = fmaxf(m_[1], fmaxf(rmx[qloc1][0], rmx[qloc1][1]));
      sc1 = __expf(m_[1] - mn); m_[1] = mn;
    }
    l_[0] *= sc0; l_[1] *= sc1;
    #pragma unroll
    for (int i = 0; i < 2; i++){
      #pragma unroll
      for (int rr = 0; rr < 4; rr++){ Oa[i][0][rr] *= sc0; Oa[i][1][rr] *= sc1; }
    }

    // P = exp(S - m); psum; pack to bf16 pairs; one b64 store per (i,j)
    float ps0 = 0.0f, ps1 = 0.0f;
    #pragma unroll
    for (int i = 0; i < 2; i++){
      #pragma unroll
      for (int j = 0; j < 2; j++){
        const float mj = j ? m_[1] : m_[0];
        float p0 = __expf(s[i][j][0] - mj);
        float p1 = __expf(s[i][j][1] - mj);
        float p2 = __expf(s[i][j][2] - mj);
        float p3 = __expf(s[i][j][3] - mj);
        float s4 = (p0 + p1) + (p2 + p3);
        if (j == 0) ps0 += s4; else ps1 += s4;
        const int qq = j ? qloc1 : qloc0;
        const int sw = (i * 2 + (quad >> 1)) ^ ((qq >> 1) & 3);
        uint2 w; w.x = cvtpk(p0, p1); w.y = cvtpk(p2, p3);
        *(uint2*)&Ps[wm][qq * 32 + sw * 8 + (quad & 1) * 4] = w;
      }
    }
    ps0 += __shfl_xor(ps0, 16); ps0 += __shfl_xor(ps0, 32);
    ps1 += __shfl_xor(ps1, 16); ps1 += __shfl_xor(ps1, 32);
    if (quad == 0){ rsm[qloc0][wm] = ps0; rsm[qloc1][wm] = ps1; }
    asm volatile("s_waitcnt lgkmcnt(0)\n\ts_barrier" ::: "memory");
    l_[0] += rsm[qloc0][0] + rsm[qloc0][1];
    l_[1] += rsm[qloc1][0] + rsm[qloc1][1];

    // PV: O^T[d][q] += sum_k V^T[d][k] P[q][k]
    #pragma unroll
    for (int ks = 0; ks < 2; ks++){
      short8 vf[2], pf[2];
      vf[0] = *(const short8*)&Vs[cur][ks][(wm * 32 + l16) * 32 + rs];
      vf[1] = *(const short8*)&Vs[cur][ks][(wm * 32 + 16 + l16) * 32 + rs];
      pf[0] = *(const short8*)&Ps[ks][(wn * 32 + l16) * 32 + rs];
      pf[1] = *(const short8*)&Ps[ks][(wn * 32 + 16 + l16) * 32 + rs];
      Oa[0][0] = __builtin_amdgcn_mfma_f32_16x16x32_bf16(vf[0], pf[0], Oa[0][0], 0, 0, 0);
      Oa[0][1] = __builtin_amdgcn_mfma_f32_16x16x32_bf16(vf[0], pf[1], Oa[0][1], 0, 0, 0);
      Oa[1][0] = __builtin_amdgcn_mfma_f32_16x16x32_bf16(vf[1], pf[0], Oa[1][0], 0, 0, 0);
      Oa[1][1] = __builtin_amdgcn_mfma_f32_16x16x32_bf16(vf[1], pf[1], Oa[1][1], 0, 0, 0);
    }
    if (t < 15) asm volatile("s_waitcnt vmcnt(0) lgkmcnt(0)\n\ts_barrier" ::: "memory");
  }

  // epilogue: O[token q][h*64+d] = Oa^T / l ; 4 consecutive d per 8B store
  const float inv0 = 1.0f / l_[0], inv1 = 1.0f / l_[1];
  #pragma unroll
  for (int i = 0; i < 2; i++){
    #pragma unroll
    for (int j = 0; j < 2; j++){
      const float invj = j ? inv1 : inv0;
      const int qq = j ? qloc1 : qloc0;
      const long ro = ((long)(f.oBase + bl) * 1024 + q0 + qq) * 768 + h * 64
                    + wm * 32 + i * 16 + quad * 4;
      u16x4 o;
      o.x = f2b(Oa[i][j][0] * invj);
      o.y = f2b(Oa[i][j][1] * invj);
      o.z = f2b(Oa[i][j][2] * invj);
      o.w = f2b(Oa[i][j][3] * invj);
      *(u16x4*)&f.O[ro] = o;
    }
  }
}

extern "C" void kernel_launch(void* const* d_in, const int* in_sizes, int n_in,
                              void* d_out, int out_size, void* d_ws, size_t ws_size,
                              hipStream_t stream){
  (void)in_sizes; (void)n_in; (void)out_size;
  const float* patches = (const float*)d_in[0];
  const void*  mask    = d_in[1];
  const float* mtok    = (const float*)d_in[2];
  const float* patch_w = (const float*)d_in[3];
  const float* patch_b = (const float*)d_in[4];
  const float* pos_emb = (const float*)d_in[5];
  const float* rel_b   = (const float*)d_in[6];
  const float* in_w    = (const float*)d_in[7];
  const float* in_b    = (const float*)d_in[8];
  const float* attn_ow = (const float*)d_in[9];
  const float* attn_ob = (const float*)d_in[10];
  const float* ln1_s   = (const float*)d_in[11];
  const float* ln1_b   = (const float*)d_in[12];
  const float* ffn_w1  = (const float*)d_in[13];
  const float* ffn_b1  = (const float*)d_in[14];
  const float* ffn_w2  = (const float*)d_in[15];
  const float* ffn_b2  = (const float*)d_in[16];
  const float* ln2_s   = (const float*)d_in[17];
  const float* ln2_b   = (const float*)d_in[18];
  const float* head_w  = (const float*)d_in[19];
  const float* head_b  = (const float*)d_in[20];

  // ws base layout (known safe)
  char* ws = (char*)d_ws;
  int* mode = (int*)ws;
  u16* X  = (u16*)(ws + 256);            // [4096,768]
  u16* WA = X + 3145728;                 // up to [3072,768]
  u16* WB = WA + 2359296;                // up to [3072,768]
  char* EX = (char*)(WB + 2359296);      // extra region
  long extra = (long)ws_size - 15728896L;
  const bool bigWs = extra >= 25165824L; // QK+VT+O (= H) fits in ws extra

  u16*   dout16 = (u16*)d_out;
  float* doutf  = (float*)d_out;

  // big-ws pointers (attention phase)
  u16* QKp = (u16*)EX;                   // [4096,1536]
  u16* VTp = QKp + 6291456;              // [48*64,1024]
  u16* Op  = VTp + 3145728;              // [4096,768]
  u16* Hp  = (u16*)EX;                   // [4096,3072] (ffn phase, aliased)
  // small-ws pointers: attention staged in d_out halves
  u16* O16  = dout16;                    // [4096,768]
  u16* QKh  = dout16 + 3145728;          // [2048,1536]
  u16* VTh  = dout16 + 6291456;          // [24*64,1024]
  u16* XRb  = dout16 + 3145728;          // [4096,768] (after QKh/VTh dead)
  u16* Hc   = dout16;                    // [2048,3072]
  u16* XRc  = dout16 + 6291456;          // [2048,768]

  detect_k<<<dim3(1), dim3(256), 0, stream>>>((const u16*)mask, mode);

  GP g; FP fp;
  // embed (MP in d_out) + patch projection -> X
  wconv_k<<<dim3(576), dim3(256), 0, stream>>>(patch_w, WA);
  embed_k<<<dim3(4096), dim3(256), 0, stream>>>(patches, mask, mode, mtok, dout16);
  g = {};
  g.A = dout16; g.lda = 768; g.W = WA; g.ldw = 768; g.wclamp = 767;
  g.C = X; g.ldc = 768; g.N = 768; g.K = 768;
  g.bias = patch_b; g.pose = pos_emb;
  glaunch(6, dim3(12, 64, 1), g, stream);

  for (int l = 0; l < 6; l++){
    wconv_k<<<dim3(1728), dim3(256), 0, stream>>>(in_w + (long)l * 1769472, WA);
    wconv_k<<<dim3(576),  dim3(256), 0, stream>>>(attn_ow + (long)l * 589824, WB);

    if (bigWs){
      // qkv full-M
      g = {};
      g.A = X; g.lda = 768; g.W = WA; g.ldw = 768; g.wclamp = 2303;
      g.bias = in_b + (long)l * 2304;
      g.C = QKp; g.Cv = VTp; g.N = 2304; g.K = 768;
      glaunch(0, dim3(36, 64, 1), g, stream);

      fp = {};
      fp.QK = QKp; fp.VT = VTp; fp.O = Op; fp.relb = rel_b; fp.oBase = 0;
      flash_k<<<dim3(16, 48), dim3(256), 0, stream>>>(fp);

      // o-proj + residual -> XR(d_out), LN1 -> X
      g = {};
      g.A = Op; g.lda = 768; g.W = WB; g.ldw = 768; g.wclamp = 767;
      g.bias = attn_ob + (long)l * 768; g.resid = X;
      g.C = dout16; g.ldc = 768; g.N = 768; g.K = 768;
      glaunch(3, dim3(12, 64, 1), g, stream);
      ln_k<<<dim3(4096), dim3(256), 0, stream>>>(dout16, X, ln1_s + l * 768, ln1_b + l * 768);
    } else {
      for (int hb = 0; hb < 2; hb++){
        g = {};
        g.A = X + (long)hb * 1572864; g.lda = 768;
        g.W = WA; g.ldw = 768; g.wclamp = 2303;
        g.bias = in_b + (long)l * 2304;
        g.C = QKh; g.Cv = VTh; g.N = 2304; g.K = 768;
        glaunch(0, dim3(36, 32, 1), g, stream);

        fp = {};
        fp.QK = QKh; fp.VT = VTh; fp.O = O16; fp.relb = rel_b; fp.oBase = hb * 2;
        flash_k<<<dim3(16, 24), dim3(256), 0, stream>>>(fp);
      }
      g = {};
      g.A = O16; g.lda = 768; g.W = WB; g.ldw = 768; g.wclamp = 767;
      g.bias = attn_ob + (long)l * 768; g.resid = X;
      g.C = XRb; g.ldc = 768; g.N = 768; g.K = 768;
      glaunch(3, dim3(12, 64, 1), g, stream);
      ln_k<<<dim3(4096), dim3(256), 0, stream>>>(XRb, X, ln1_s + l * 768, ln1_b + l * 768);
    }

    wconv_k<<<dim3(2304), dim3(256), 0, stream>>>(ffn_w1 + (long)l * 2359296, WA);
    wconv_k<<<dim3(2304), dim3(256), 0, stream>>>(ffn_w2 + (long)l * 2359296, WB);

    if (bigWs){
      g = {};
      g.A = X; g.lda = 768; g.W = WA; g.ldw = 768; g.wclamp = 3071;
      g.bias = ffn_b1 + (long)l * 3072;
      g.C = Hp; g.ldc = 3072; g.N = 3072; g.K = 768;
      glaunch(4, dim3(48, 64, 1), g, stream);
      g = {};
      g.A = Hp; g.lda = 3072; g.W = WB; g.ldw = 3072; g.wclamp = 767;
      g.bias = ffn_b2 + (long)l * 768; g.resid = X;
      g.C = dout16; g.ldc = 768; g.N = 768; g.K = 3072;
      glaunch(3, dim3(12, 64, 1), g, stream);
      ln_k<<<dim3(4096), dim3(256), 0, stream>>>(dout16, X, ln2_s + l * 768, ln2_b + l * 768);
    } else {
      for (int cc = 0; cc < 2; cc++){
        u16* Xc = X + (long)cc * 1572864;
        g = {};
        g.A = Xc; g.lda = 768; g.W = WA; g.ldw = 768; g.wclamp = 3071;
        g.bias = ffn_b1 + (long)l * 3072;
        g.C = Hc; g.ldc = 3072; g.N = 3072; g.K = 768;
        glaunch(4, dim3(48, 32, 1), g, stream);
        g = {};
        g.A = Hc; g.lda = 3072; g.W = WB; g.ldw = 3072; g.wclamp = 767;
        g.bias = ffn_b2 + (long)l * 768; g.resid = Xc;
        g.C = XRc; g.ldc = 768; g.N = 768; g.K = 3072;
        glaunch(3, dim3(12, 32, 1), g, stream);
        ln_k<<<dim3(2048), dim3(256), 0, stream>>>(XRc, Xc, ln2_s + l * 768, ln2_b + l * 768);
      }
    }
  }

  // head: logits (f32) -> d_out
  wconv_k<<<dim3(768), dim3(256), 0, stream>>>(head_w, WA);
  g = {};
  g.A = X; g.lda = 768; g.W = WA; g.ldw = 768; g.wclamp = 1023;
  g.bias = head_b;
  g.Cf = doutf; g.ldc = 1024; g.N = 1024; g.K = 768;
  glaunch(5, dim3(16, 64, 1), g, stream);
  maskout_k<<<dim3(16), dim3(256), 0, stream>>>(mask, mode, doutf + 4194304);
}